// Round 2
// baseline (570.718 us; speedup 1.0000x reference)
//
#include <hip/hip_runtime.h>
#include <hip/hip_bf16.h>
#include <stdint.h>
#include <math.h>

typedef __bf16 bf16_t;
typedef __bf16 bf16x8 __attribute__((ext_vector_type(8)));
typedef __bf16 bf16x4 __attribute__((ext_vector_type(4)));
typedef float  f32x4  __attribute__((ext_vector_type(4)));

#define S_CTX 2048
#define NH    16
#define DM    1024
#define DH    64

// ws layout (bf16 element offsets)
#define WS_WT   0                      // wqT, wkT, wvT: 3 * 16*64*1024
#define WS_WOT  (3*1048576)            // woT: 16*1024*64
#define WS_Q    (4*1048576)            // (h,s,e) 16*2048*64
#define WS_K    (WS_Q  + 2097152)
#define WS_VT   (WS_K  + 2097152)      // (h,e,s)
#define WS_Z    (WS_VT + 2097152)      // (h,s,e)
// total = 12,582,912 bf16 = 24 MiB

// Stage a 64x64 bf16 tile (rows x cols) from ws, row stride in elements.
__device__ __forceinline__ void stage_tile(const bf16_t* __restrict__ g, int row_stride,
                                           bf16_t* lds, int tid) {
#pragma unroll
  for (int i = 0; i < 2; i++) {
    int r = (tid >> 3) + i * 32;
    int c = (tid & 7) << 3;
    *reinterpret_cast<uint4*>(lds + r * 64 + c) =
        *reinterpret_cast<const uint4*>(g + r * row_stride + c);
  }
}

// Stage a 64x64 fp32 tile from global, converting to bf16 in LDS.
__device__ __forceinline__ void stage_f32(const float* __restrict__ g, int row_stride,
                                          bf16_t* lds, int tid) {
#pragma unroll
  for (int i = 0; i < 4; i++) {
    int idx = tid + i * 256;          // 0..1023
    int r = idx >> 4;                 // 0..63
    int c = (idx & 15) << 2;          // 0..60
    float4 v = *reinterpret_cast<const float4*>(g + r * row_stride + c);
    bf16x4 b;
    b[0] = (bf16_t)v.x; b[1] = (bf16_t)v.y; b[2] = (bf16_t)v.z; b[3] = (bf16_t)v.w;
    *reinterpret_cast<bf16x4*>(lds + r * 64 + c) = b;
  }
}

// ---------------- weight transpose: fp32 W(n,R,C) -> bf16 WT(n,C,R) ---------
__global__ __launch_bounds__(256) void transpose_w(const float* __restrict__ wq,
                                                   const float* __restrict__ wk,
                                                   const float* __restrict__ wv,
                                                   const float* __restrict__ wo,
                                                   bf16_t* __restrict__ ws) {
  __shared__ bf16_t tl[64 * 68];  // +4 pad: keeps bf16x4 stores 8B aligned
  int m = blockIdx.z, h = blockIdx.y, t = blockIdx.x, tid = threadIdx.x;
  const float* in; bf16_t* out; int R, C, r0, c0;
  if (m < 3) { in = (m == 0) ? wq : (m == 1) ? wk : wv; out = ws + m * 1048576;
               R = 1024; C = 64; r0 = t * 64; c0 = 0; }
  else       { in = wo; out = ws + WS_WOT; R = 64; C = 1024; r0 = 0; c0 = t * 64; }
  in  += h * 65536;
  out += h * 65536;
#pragma unroll
  for (int i = 0; i < 4; i++) {
    int idx = tid + i * 256;
    int r = idx >> 4, c = (idx & 15) << 2;
    float4 v = *reinterpret_cast<const float4*>(in + (r0 + r) * C + c0 + c);
    bf16x4 b;
    b[0] = (bf16_t)v.x; b[1] = (bf16_t)v.y; b[2] = (bf16_t)v.z; b[3] = (bf16_t)v.w;
    *reinterpret_cast<bf16x4*>(tl + r * 68 + c) = b;
  }
  __syncthreads();
#pragma unroll
  for (int i = 0; i < 2; i++) {
    int oc = (tid >> 3) + i * 32, ok = (tid & 7) << 3;
    bf16x8 v;
#pragma unroll
    for (int j = 0; j < 8; j++) v[j] = tl[(ok + j) * 68 + oc];
    *reinterpret_cast<bf16x8*>(out + (c0 + oc) * R + r0 + ok) = v;
  }
}

// ---------------- QKV projection + rotary -----------------------------------
__global__ __launch_bounds__(256) void qkv_proj(const float* __restrict__ xq,
                                                const float* __restrict__ xk,
                                                const float* __restrict__ xv,
                                                const float* __restrict__ bq,
                                                const float* __restrict__ bk,
                                                const float* __restrict__ bv,
                                                bf16_t* __restrict__ ws) {
  __shared__ bf16_t Al[64 * 64];
  __shared__ bf16_t Bl[64 * 64];
  int st = blockIdx.x, h = blockIdx.y, m = blockIdx.z;
  int tid = threadIdx.x, w = tid >> 6, lane = tid & 63, quad = lane >> 4, l15 = lane & 15;
  const float*  in   = (m == 0) ? xq : (m == 1) ? xk : xv;
  const bf16_t* wT   = ws + m * 1048576 + h * 65536;   // (e,k) rows
  const float*  bias = (m == 0) ? bq : (m == 1) ? bk : bv;
  int s0 = st * 64;
  f32x4 acc[4];
#pragma unroll
  for (int t = 0; t < 4; t++) acc[t] = (f32x4){0.f, 0.f, 0.f, 0.f};
  const float* Ab = in + (s0 * 16 + h) * 1024;

  for (int k0 = 0; k0 < 1024; k0 += 64) {
    stage_f32(Ab + k0, 16384, Al, tid);    // rows s (stride N_HEADS*DM)
    stage_tile(wT + k0, 1024, Bl, tid);    // rows e (stride DM), bf16
    __syncthreads();
#pragma unroll
    for (int ks = 0; ks < 2; ks++) {
      bf16x8 af = *reinterpret_cast<const bf16x8*>(Al + (w * 16 + l15) * 64 + ks * 32 + quad * 8);
#pragma unroll
      for (int t = 0; t < 4; t++) {
        bf16x8 bfr = *reinterpret_cast<const bf16x8*>(Bl + (t * 16 + l15) * 64 + ks * 32 + quad * 8);
        acc[t] = __builtin_amdgcn_mfma_f32_16x16x32_bf16(af, bfr, acc[t], 0, 0, 0);
      }
    }
    __syncthreads();
  }
  // bias (zeros in practice, but correct in general)
#pragma unroll
  for (int t = 0; t < 4; t++) {
    float bval = bias[h * 64 + t * 16 + l15];
#pragma unroll
    for (int r = 0; r < 4; r++) acc[t][r] += bval;
  }

  if (m < 2) {
    // rotary: cols c and c+32 live in tiles t and t+2 on the SAME lane/reg
    bf16_t* outp = ws + ((m == 0) ? WS_Q : WS_K) + h * (2048 * 64);
#pragma unroll
    for (int t = 0; t < 2; t++) {
      int c_lo = t * 16 + l15;                       // 0..31
      float freq = powf(10000.0f, (float)c_lo * (1.0f / 32.0f));
#pragma unroll
      for (int r = 0; r < 4; r++) {
        int s = s0 + w * 16 + quad * 4 + r;
        float ang = (float)s / freq;
        float sv = sinf(ang), cv = cosf(ang);
        float xl = acc[t][r], xh = acc[t + 2][r];
        acc[t][r]     = xl * cv - xh * sv;
        acc[t + 2][r] = xh * cv + xl * sv;
      }
    }
#pragma unroll
    for (int t = 0; t < 4; t++)
#pragma unroll
      for (int r = 0; r < 4; r++) {
        int s = s0 + w * 16 + quad * 4 + r;
        outp[s * 64 + t * 16 + l15] = (bf16_t)acc[t][r];
      }
  } else {
    // V stored transposed: (h, e, s)
    bf16_t* outp = ws + WS_VT + h * (64 * 2048);
#pragma unroll
    for (int t = 0; t < 4; t++) {
      int e = t * 16 + l15;
      int s = s0 + w * 16 + quad * 4;
      bf16x4 v;
#pragma unroll
      for (int r = 0; r < 4; r++) v[r] = (bf16_t)acc[t][r];
      *reinterpret_cast<bf16x4*>(outp + e * 2048 + s) = v;
    }
  }
}

// ---------------- flash attention (causal, online softmax) ------------------
__global__ __launch_bounds__(256) void attn(bf16_t* __restrict__ ws) {
  __shared__ bf16_t Ql[64 * 64], Kl[64 * 64], Vl[64 * 64], Pl[4 * 16 * 64];
  int qt = blockIdx.x, h = blockIdx.y;
  int tid = threadIdx.x, w = tid >> 6, lane = tid & 63, quad = lane >> 4, l15 = lane & 15;
  const bf16_t* qp  = ws + WS_Q  + h * 131072;
  const bf16_t* kp  = ws + WS_K  + h * 131072;
  const bf16_t* vtp = ws + WS_VT + h * 131072;
  bf16_t*       zp  = ws + WS_Z  + h * 131072;
  int s0 = qt * 64;

  stage_tile(qp + s0 * 64, 64, Ql, tid);

  f32x4 o[4];
#pragma unroll
  for (int t = 0; t < 4; t++) o[t] = (f32x4){0.f, 0.f, 0.f, 0.f};
  float m_i[4], l_i[4];
#pragma unroll
  for (int r = 0; r < 4; r++) { m_i[r] = -__builtin_inff(); l_i[r] = 0.f; }

  for (int j = 0; j <= qt; j++) {
    __syncthreads();                                   // prev iter done with Kl/Vl
    stage_tile(kp + j * 64 * 64, 64,   Kl, tid);       // K tile: rows kv, cols e
    stage_tile(vtp + j * 64,     2048, Vl, tid);       // V^T tile: rows e, cols kv
    __syncthreads();

    // scores S = Q K^T
    f32x4 sc[4];
#pragma unroll
    for (int t = 0; t < 4; t++) sc[t] = (f32x4){0.f, 0.f, 0.f, 0.f};
#pragma unroll
    for (int ks = 0; ks < 2; ks++) {
      bf16x8 af = *reinterpret_cast<const bf16x8*>(Ql + (w * 16 + l15) * 64 + ks * 32 + quad * 8);
#pragma unroll
      for (int t = 0; t < 4; t++) {
        bf16x8 bfr = *reinterpret_cast<const bf16x8*>(Kl + (t * 16 + l15) * 64 + ks * 32 + quad * 8);
        sc[t] = __builtin_amdgcn_mfma_f32_16x16x32_bf16(af, bfr, sc[t], 0, 0, 0);
      }
    }
    // scale + causal mask
#pragma unroll
    for (int t = 0; t < 4; t++) {
      int kvc = j * 64 + t * 16 + l15;
#pragma unroll
      for (int r = 0; r < 4; r++) {
        int qrow = s0 + w * 16 + quad * 4 + r;
        float sv = sc[t][r] * 0.125f;
        sc[t][r] = (kvc > qrow) ? -1e30f : sv;
      }
    }
    // online softmax per row (16 lanes of a quad share each row)
    float p[4][4], alpha[4];
#pragma unroll
    for (int r = 0; r < 4; r++) {
      float mx = fmaxf(fmaxf(sc[0][r], sc[1][r]), fmaxf(sc[2][r], sc[3][r]));
#pragma unroll
      for (int off = 1; off < 16; off <<= 1) mx = fmaxf(mx, __shfl_xor(mx, off));
      float mn = fmaxf(m_i[r], mx);
      alpha[r] = __expf(m_i[r] - mn);
      float rs = 0.f;
#pragma unroll
      for (int t = 0; t < 4; t++) { p[t][r] = __expf(sc[t][r] - mn); rs += p[t][r]; }
#pragma unroll
      for (int off = 1; off < 16; off <<= 1) rs += __shfl_xor(rs, off);
      l_i[r] = l_i[r] * alpha[r] + rs;
      m_i[r] = mn;
    }
    // P (C-layout) -> LDS -> A-layout
#pragma unroll
    for (int t = 0; t < 4; t++)
#pragma unroll
      for (int r = 0; r < 4; r++)
        Pl[w * 1024 + (quad * 4 + r) * 64 + t * 16 + l15] = (bf16_t)p[t][r];
    // rescale O
#pragma unroll
    for (int t = 0; t < 4; t++)
#pragma unroll
      for (int r = 0; r < 4; r++) o[t][r] *= alpha[r];
    __syncthreads();   // P write -> P read ordering
    // O += P V
#pragma unroll
    for (int ks = 0; ks < 2; ks++) {
      bf16x8 af = *reinterpret_cast<const bf16x8*>(Pl + w * 1024 + l15 * 64 + ks * 32 + quad * 8);
#pragma unroll
      for (int t = 0; t < 4; t++) {
        bf16x8 bfr = *reinterpret_cast<const bf16x8*>(Vl + (t * 16 + l15) * 64 + ks * 32 + quad * 8);
        o[t] = __builtin_amdgcn_mfma_f32_16x16x32_bf16(af, bfr, o[t], 0, 0, 0);
      }
    }
  }
  // normalize + store z (h,s,e)
  float inv[4];
#pragma unroll
  for (int r = 0; r < 4; r++) inv[r] = 1.0f / l_i[r];
#pragma unroll
  for (int t = 0; t < 4; t++)
#pragma unroll
    for (int r = 0; r < 4; r++) {
      int s = s0 + w * 16 + quad * 4 + r;
      zp[s * 64 + t * 16 + l15] = (bf16_t)(o[t][r] * inv[r]);
    }
}

// ---------------- output projection (fp32 out) ------------------------------
__global__ __launch_bounds__(256) void out_proj(const bf16_t* __restrict__ ws,
                                                const float* __restrict__ bo,
                                                float* __restrict__ out) {
  __shared__ bf16_t Al[64 * 64], Bl[64 * 64];
  int st = blockIdx.x >> 4, dt = blockIdx.x & 15, h = blockIdx.y;
  int tid = threadIdx.x, w = tid >> 6, lane = tid & 63, quad = lane >> 4, l15 = lane & 15;
  int s0 = st * 64, d0 = dt * 64;
  const bf16_t* zp = ws + WS_Z + h * 131072 + s0 * 64;   // (s,e)
  const bf16_t* wo = ws + WS_WOT + h * 65536 + d0 * 64;  // (d,e)
  stage_tile(zp, 64, Al, tid);
  stage_tile(wo, 64, Bl, tid);
  __syncthreads();
  f32x4 acc[4];
#pragma unroll
  for (int t = 0; t < 4; t++) acc[t] = (f32x4){0.f, 0.f, 0.f, 0.f};
#pragma unroll
  for (int ks = 0; ks < 2; ks++) {
    bf16x8 af = *reinterpret_cast<const bf16x8*>(Al + (w * 16 + l15) * 64 + ks * 32 + quad * 8);
#pragma unroll
    for (int t = 0; t < 4; t++) {
      bf16x8 bfr = *reinterpret_cast<const bf16x8*>(Bl + (t * 16 + l15) * 64 + ks * 32 + quad * 8);
      acc[t] = __builtin_amdgcn_mfma_f32_16x16x32_bf16(af, bfr, acc[t], 0, 0, 0);
    }
  }
#pragma unroll
  for (int t = 0; t < 4; t++) {
    float bval = bo[d0 + t * 16 + l15] * (1.0f / 16.0f);
#pragma unroll
    for (int r = 0; r < 4; r++) {
      int s = s0 + w * 16 + quad * 4 + r;
      out[(s * 16 + h) * 1024 + d0 + t * 16 + l15] = acc[t][r] + bval;
    }
  }
}

extern "C" void kernel_launch(void* const* d_in, const int* in_sizes, int n_in,
                              void* d_out, int out_size, void* d_ws, size_t ws_size,
                              hipStream_t stream) {
  const float* xq = (const float*)d_in[0];
  const float* xk = (const float*)d_in[1];
  const float* xv = (const float*)d_in[2];
  const float* wq = (const float*)d_in[3];
  const float* bq = (const float*)d_in[4];
  const float* wk = (const float*)d_in[5];
  const float* bk = (const float*)d_in[6];
  const float* wv = (const float*)d_in[7];
  const float* bv = (const float*)d_in[8];
  const float* wo = (const float*)d_in[9];
  const float* bo = (const float*)d_in[10];
  bf16_t* ws  = (bf16_t*)d_ws;
  float*  out = (float*)d_out;

  hipLaunchKernelGGL(transpose_w, dim3(16, 16, 4), dim3(256), 0, stream, wq, wk, wv, wo, ws);
  hipLaunchKernelGGL(qkv_proj,    dim3(32, 16, 3), dim3(256), 0, stream, xq, xk, xv, bq, bk, bv, ws);
  hipLaunchKernelGGL(attn,        dim3(32, 16),    dim3(256), 0, stream, ws);
  hipLaunchKernelGGL(out_proj,    dim3(512, 16),   dim3(256), 0, stream, ws, bo, out);
}

// Round 3
// 556.608 us; speedup vs baseline: 1.0253x; 1.0253x over previous
//
#include <hip/hip_runtime.h>
#include <hip/hip_bf16.h>
#include <stdint.h>
#include <math.h>

typedef __bf16 bf16_t;
typedef __bf16 bf16x8 __attribute__((ext_vector_type(8)));
typedef __bf16 bf16x4 __attribute__((ext_vector_type(4)));
typedef float  f32x4  __attribute__((ext_vector_type(4)));

#define S_CTX 2048
#define NH    16
#define DM    1024
#define DH    64

// ws layout (bf16 element offsets)
#define WS_WT   0                      // wqT, wkT, wvT: 3 * 16*64*1024  (e,k)
#define WS_WOT  (3*1048576)            // woT: 16*1024*64  (d,e)
#define WS_Q    (4*1048576)            // (h,s,e) 16*2048*64
#define WS_K    (WS_Q  + 2097152)
#define WS_VT   (WS_K  + 2097152)      // (h,e,s)
#define WS_Z    (WS_VT + 2097152)      // (h,s,e)

// ---------------- weight transpose: fp32 W(n,R,C) -> bf16 WT(n,C,R) ---------
__global__ __launch_bounds__(256) void transpose_w(const float* __restrict__ wq,
                                                   const float* __restrict__ wk,
                                                   const float* __restrict__ wv,
                                                   const float* __restrict__ wo,
                                                   bf16_t* __restrict__ ws) {
  __shared__ bf16_t tl[64 * 68];
  int m = blockIdx.z, h = blockIdx.y, t = blockIdx.x, tid = threadIdx.x;
  const float* in; bf16_t* out; int R, C, r0, c0;
  if (m < 3) { in = (m == 0) ? wq : (m == 1) ? wk : wv; out = ws + m * 1048576;
               R = 1024; C = 64; r0 = t * 64; c0 = 0; }
  else       { in = wo; out = ws + WS_WOT; R = 64; C = 1024; r0 = 0; c0 = t * 64; }
  in  += h * 65536;
  out += h * 65536;
#pragma unroll
  for (int i = 0; i < 4; i++) {
    int idx = tid + i * 256;
    int r = idx >> 4, c = (idx & 15) << 2;
    float4 v = *reinterpret_cast<const float4*>(in + (r0 + r) * C + c0 + c);
    bf16x4 b;
    b[0] = (bf16_t)v.x; b[1] = (bf16_t)v.y; b[2] = (bf16_t)v.z; b[3] = (bf16_t)v.w;
    *reinterpret_cast<bf16x4*>(tl + r * 68 + c) = b;
  }
  __syncthreads();
#pragma unroll
  for (int i = 0; i < 2; i++) {
    int oc = (tid >> 3) + i * 32, ok = (tid & 7) << 3;
    bf16x8 v;
#pragma unroll
    for (int j = 0; j < 8; j++) v[j] = tl[(ok + j) * 68 + oc];
    *reinterpret_cast<bf16x8*>(out + (c0 + oc) * R + r0 + ok) = v;
  }
}

// ---------------- QKV projection + rotary -----------------------------------
// 128 s-rows x 64 cols per block, K-step 128, 8 iters, 32 MFMA/wave/iter.
__global__ __launch_bounds__(256) void qkv_proj(const float* __restrict__ xq,
                                                const float* __restrict__ xk,
                                                const float* __restrict__ xv,
                                                const float* __restrict__ bq,
                                                const float* __restrict__ bk,
                                                const float* __restrict__ bv,
                                                bf16_t* __restrict__ ws) {
  __shared__ bf16_t Al[128 * 136];   // (s, k) padded
  __shared__ bf16_t Bl[64 * 136];    // (e, k) padded
  int st = blockIdx.x, h = blockIdx.y, m = blockIdx.z;
  int tid = threadIdx.x, w = tid >> 6, lane = tid & 63, quad = lane >> 4, l15 = lane & 15;
  const float*  in   = (m == 0) ? xq : (m == 1) ? xk : xv;
  const bf16_t* wT   = ws + m * 1048576 + h * 65536;
  const float*  bias = (m == 0) ? bq : (m == 1) ? bk : bv;
  int s0 = st * 128;
  const float* Ab = in + (s0 * 16 + h) * 1024;   // row stride 16*1024

  f32x4 acc[2][4];
#pragma unroll
  for (int rt = 0; rt < 2; rt++)
#pragma unroll
    for (int t = 0; t < 4; t++) acc[rt][t] = (f32x4){0.f, 0.f, 0.f, 0.f};

  for (int k0 = 0; k0 < 1024; k0 += 128) {
    // stage A: 128x128 fp32 -> bf16
#pragma unroll
    for (int i = 0; i < 8; i++) {
      int g = tid + i * 256;
      int r = g >> 4, cg = g & 15;
      const float* p = Ab + r * 16384 + k0 + cg * 8;
      float4 v0 = *reinterpret_cast<const float4*>(p);
      float4 v1 = *reinterpret_cast<const float4*>(p + 4);
      bf16x8 b;
      b[0] = (bf16_t)v0.x; b[1] = (bf16_t)v0.y; b[2] = (bf16_t)v0.z; b[3] = (bf16_t)v0.w;
      b[4] = (bf16_t)v1.x; b[5] = (bf16_t)v1.y; b[6] = (bf16_t)v1.z; b[7] = (bf16_t)v1.w;
      *reinterpret_cast<bf16x8*>(Al + r * 136 + cg * 8) = b;
    }
    // stage B: 64x128 bf16
#pragma unroll
    for (int i = 0; i < 4; i++) {
      int g = tid + i * 256;
      int r = g >> 4, cg = g & 15;
      *reinterpret_cast<uint4*>(Bl + r * 136 + cg * 8) =
          *reinterpret_cast<const uint4*>(wT + r * 1024 + k0 + cg * 8);
    }
    __syncthreads();
#pragma unroll
    for (int ks = 0; ks < 4; ks++) {
      bf16x8 a0 = *reinterpret_cast<const bf16x8*>(Al + (w * 32 + l15) * 136 + ks * 32 + quad * 8);
      bf16x8 a1 = *reinterpret_cast<const bf16x8*>(Al + (w * 32 + 16 + l15) * 136 + ks * 32 + quad * 8);
#pragma unroll
      for (int t = 0; t < 4; t++) {
        bf16x8 bb = *reinterpret_cast<const bf16x8*>(Bl + (t * 16 + l15) * 136 + ks * 32 + quad * 8);
        acc[0][t] = __builtin_amdgcn_mfma_f32_16x16x32_bf16(a0, bb, acc[0][t], 0, 0, 0);
        acc[1][t] = __builtin_amdgcn_mfma_f32_16x16x32_bf16(a1, bb, acc[1][t], 0, 0, 0);
      }
    }
    __syncthreads();
  }
  // bias
#pragma unroll
  for (int t = 0; t < 4; t++) {
    float bval = bias[h * 64 + t * 16 + l15];
#pragma unroll
    for (int rt = 0; rt < 2; rt++)
#pragma unroll
      for (int r = 0; r < 4; r++) acc[rt][t][r] += bval;
  }

  if (m < 2) {
    bf16_t* outp = ws + ((m == 0) ? WS_Q : WS_K) + h * (2048 * 64);
#pragma unroll
    for (int t = 0; t < 2; t++) {
      int c_lo = t * 16 + l15;
      float freq = powf(10000.0f, (float)c_lo * (1.0f / 32.0f));
#pragma unroll
      for (int rt = 0; rt < 2; rt++)
#pragma unroll
        for (int r = 0; r < 4; r++) {
          int s = s0 + w * 32 + rt * 16 + quad * 4 + r;
          float ang = (float)s / freq;
          float sv = sinf(ang), cv = cosf(ang);
          float xl = acc[rt][t][r], xh = acc[rt][t + 2][r];
          acc[rt][t][r]     = xl * cv - xh * sv;
          acc[rt][t + 2][r] = xh * cv + xl * sv;
        }
    }
#pragma unroll
    for (int rt = 0; rt < 2; rt++)
#pragma unroll
      for (int t = 0; t < 4; t++)
#pragma unroll
        for (int r = 0; r < 4; r++) {
          int s = s0 + w * 32 + rt * 16 + quad * 4 + r;
          outp[s * 64 + t * 16 + l15] = (bf16_t)acc[rt][t][r];
        }
  } else {
    bf16_t* outp = ws + WS_VT + h * (64 * 2048);
#pragma unroll
    for (int rt = 0; rt < 2; rt++)
#pragma unroll
      for (int t = 0; t < 4; t++) {
        int e = t * 16 + l15;
        int sbase = s0 + w * 32 + rt * 16 + quad * 4;
        bf16x4 v;
#pragma unroll
        for (int r = 0; r < 4; r++) v[r] = (bf16_t)acc[rt][t][r];
        *reinterpret_cast<bf16x4*>(outp + e * 2048 + sbase) = v;
      }
  }
}

// ---------------- flash attention (causal, online softmax), KV-step 128 -----
__global__ __launch_bounds__(256) void attn(bf16_t* __restrict__ ws) {
  __shared__ bf16_t Ql[64 * 72];      // (q, e)
  __shared__ bf16_t Kl[128 * 72];     // (kv, e)
  __shared__ bf16_t Vl[64 * 136];     // (e, kv)
  __shared__ bf16_t Pl[4 * 16 * 136]; // per-wave (q, kv)
  int qt = blockIdx.x, h = blockIdx.y;
  int tid = threadIdx.x, w = tid >> 6, lane = tid & 63, quad = lane >> 4, l15 = lane & 15;
  const bf16_t* qp  = ws + WS_Q  + h * 131072;
  const bf16_t* kp  = ws + WS_K  + h * 131072;
  const bf16_t* vtp = ws + WS_VT + h * 131072;
  bf16_t*       zp  = ws + WS_Z  + h * 131072;
  int s0 = qt * 64;

  // stage Q: 64x64
#pragma unroll
  for (int i = 0; i < 2; i++) {
    int g = tid + i * 256;
    int r = g >> 3, cg = g & 7;
    *reinterpret_cast<uint4*>(Ql + r * 72 + cg * 8) =
        *reinterpret_cast<const uint4*>(qp + (s0 + r) * 64 + cg * 8);
  }

  f32x4 o[4];
#pragma unroll
  for (int t = 0; t < 4; t++) o[t] = (f32x4){0.f, 0.f, 0.f, 0.f};
  float m_i[4], l_i[4];
#pragma unroll
  for (int r = 0; r < 4; r++) { m_i[r] = -__builtin_inff(); l_i[r] = 0.f; }
  bf16_t* Plw = Pl + w * (16 * 136);

  int jmax = qt >> 1;
  for (int j = 0; j <= jmax; j++) {
    __syncthreads();
    // stage K: 128 x 64
#pragma unroll
    for (int i = 0; i < 4; i++) {
      int g = tid + i * 256;
      int r = g >> 3, cg = g & 7;
      *reinterpret_cast<uint4*>(Kl + r * 72 + cg * 8) =
          *reinterpret_cast<const uint4*>(kp + (j * 128 + r) * 64 + cg * 8);
    }
    // stage V^T: 64 x 128
#pragma unroll
    for (int i = 0; i < 4; i++) {
      int g = tid + i * 256;
      int r = g >> 4, cg = g & 15;
      *reinterpret_cast<uint4*>(Vl + r * 136 + cg * 8) =
          *reinterpret_cast<const uint4*>(vtp + r * 2048 + j * 128 + cg * 8);
    }
    __syncthreads();

    // scores: 16 q-rows/wave x 128 kv
    f32x4 sc[8];
#pragma unroll
    for (int t = 0; t < 8; t++) sc[t] = (f32x4){0.f, 0.f, 0.f, 0.f};
#pragma unroll
    for (int ks = 0; ks < 2; ks++) {
      bf16x8 af = *reinterpret_cast<const bf16x8*>(Ql + (w * 16 + l15) * 72 + ks * 32 + quad * 8);
#pragma unroll
      for (int t = 0; t < 8; t++) {
        bf16x8 bfr = *reinterpret_cast<const bf16x8*>(Kl + (t * 16 + l15) * 72 + ks * 32 + quad * 8);
        sc[t] = __builtin_amdgcn_mfma_f32_16x16x32_bf16(af, bfr, sc[t], 0, 0, 0);
      }
    }
    // scale + causal mask
#pragma unroll
    for (int t = 0; t < 8; t++) {
      int kvc = j * 128 + t * 16 + l15;
#pragma unroll
      for (int r = 0; r < 4; r++) {
        int qrow = s0 + w * 16 + quad * 4 + r;
        float sv = sc[t][r] * 0.125f;
        sc[t][r] = (kvc > qrow) ? -1e30f : sv;
      }
    }
    // online softmax (rows shared by 16 lanes of a quad)
    float alpha[4];
#pragma unroll
    for (int r = 0; r < 4; r++) {
      float mx = sc[0][r];
#pragma unroll
      for (int t = 1; t < 8; t++) mx = fmaxf(mx, sc[t][r]);
#pragma unroll
      for (int off = 1; off < 16; off <<= 1) mx = fmaxf(mx, __shfl_xor(mx, off));
      float mn = fmaxf(m_i[r], mx);
      alpha[r] = __expf(m_i[r] - mn);
      float rs = 0.f;
#pragma unroll
      for (int t = 0; t < 8; t++) { sc[t][r] = __expf(sc[t][r] - mn); rs += sc[t][r]; }
#pragma unroll
      for (int off = 1; off < 16; off <<= 1) rs += __shfl_xor(rs, off);
      l_i[r] = l_i[r] * alpha[r] + rs;
      m_i[r] = mn;
    }
    // P (C-layout) -> wave-private LDS (A-layout); no barrier needed
#pragma unroll
    for (int t = 0; t < 8; t++)
#pragma unroll
      for (int r = 0; r < 4; r++)
        Plw[(quad * 4 + r) * 136 + t * 16 + l15] = (bf16_t)sc[t][r];
    // rescale O
#pragma unroll
    for (int t = 0; t < 4; t++)
#pragma unroll
      for (int r = 0; r < 4; r++) o[t][r] *= alpha[r];
    // O += P V  (K-dim = 128)
#pragma unroll
    for (int ks = 0; ks < 4; ks++) {
      bf16x8 af = *reinterpret_cast<const bf16x8*>(Plw + l15 * 136 + ks * 32 + quad * 8);
#pragma unroll
      for (int t = 0; t < 4; t++) {
        bf16x8 bfr = *reinterpret_cast<const bf16x8*>(Vl + (t * 16 + l15) * 136 + ks * 32 + quad * 8);
        o[t] = __builtin_amdgcn_mfma_f32_16x16x32_bf16(af, bfr, o[t], 0, 0, 0);
      }
    }
  }
  // normalize + store z (h,s,e)
  float inv[4];
#pragma unroll
  for (int r = 0; r < 4; r++) inv[r] = 1.0f / l_i[r];
#pragma unroll
  for (int t = 0; t < 4; t++)
#pragma unroll
    for (int r = 0; r < 4; r++) {
      int s = s0 + w * 16 + quad * 4 + r;
      zp[s * 64 + t * 16 + l15] = (bf16_t)(o[t][r] * inv[r]);
    }
}

// ---------------- output projection (fp32 out), 128x128 tile ----------------
__global__ __launch_bounds__(256) void out_proj(const bf16_t* __restrict__ ws,
                                                const float* __restrict__ bo,
                                                float* __restrict__ out) {
  __shared__ bf16_t Zl[128 * 72];   // (s, e)
  __shared__ bf16_t Wl[128 * 72];   // (d, e)
  int st = blockIdx.x >> 3, dt = blockIdx.x & 7, h = blockIdx.y;
  int tid = threadIdx.x, w = tid >> 6, lane = tid & 63, quad = lane >> 4, l15 = lane & 15;
  int s0 = st * 128, d0 = dt * 128;
  const bf16_t* zp = ws + WS_Z + h * 131072;
  const bf16_t* wo = ws + WS_WOT + h * 65536;
#pragma unroll
  for (int i = 0; i < 4; i++) {
    int g = tid + i * 256;
    int r = g >> 3, cg = g & 7;
    *reinterpret_cast<uint4*>(Zl + r * 72 + cg * 8) =
        *reinterpret_cast<const uint4*>(zp + (s0 + r) * 64 + cg * 8);
  }
#pragma unroll
  for (int i = 0; i < 4; i++) {
    int g = tid + i * 256;
    int r = g >> 3, cg = g & 7;
    *reinterpret_cast<uint4*>(Wl + r * 72 + cg * 8) =
        *reinterpret_cast<const uint4*>(wo + (d0 + r) * 64 + cg * 8);
  }
  __syncthreads();
  f32x4 acc[2][8];
#pragma unroll
  for (int rt = 0; rt < 2; rt++)
#pragma unroll
    for (int t = 0; t < 8; t++) acc[rt][t] = (f32x4){0.f, 0.f, 0.f, 0.f};
#pragma unroll
  for (int ks = 0; ks < 2; ks++) {
    bf16x8 a0 = *reinterpret_cast<const bf16x8*>(Zl + (w * 32 + l15) * 72 + ks * 32 + quad * 8);
    bf16x8 a1 = *reinterpret_cast<const bf16x8*>(Zl + (w * 32 + 16 + l15) * 72 + ks * 32 + quad * 8);
#pragma unroll
    for (int t = 0; t < 8; t++) {
      bf16x8 bb = *reinterpret_cast<const bf16x8*>(Wl + (t * 16 + l15) * 72 + ks * 32 + quad * 8);
      acc[0][t] = __builtin_amdgcn_mfma_f32_16x16x32_bf16(a0, bb, acc[0][t], 0, 0, 0);
      acc[1][t] = __builtin_amdgcn_mfma_f32_16x16x32_bf16(a1, bb, acc[1][t], 0, 0, 0);
    }
  }
#pragma unroll
  for (int t = 0; t < 8; t++) {
    float bval = bo[d0 + t * 16 + l15] * (1.0f / 16.0f);
#pragma unroll
    for (int rt = 0; rt < 2; rt++)
#pragma unroll
      for (int r = 0; r < 4; r++) {
        int s = s0 + w * 32 + rt * 16 + quad * 4 + r;
        out[(s * 16 + h) * 1024 + d0 + t * 16 + l15] = acc[rt][t][r] + bval;
      }
  }
}

extern "C" void kernel_launch(void* const* d_in, const int* in_sizes, int n_in,
                              void* d_out, int out_size, void* d_ws, size_t ws_size,
                              hipStream_t stream) {
  const float* xq = (const float*)d_in[0];
  const float* xk = (const float*)d_in[1];
  const float* xv = (const float*)d_in[2];
  const float* wq = (const float*)d_in[3];
  const float* bq = (const float*)d_in[4];
  const float* wk = (const float*)d_in[5];
  const float* bk = (const float*)d_in[6];
  const float* wv = (const float*)d_in[7];
  const float* bv = (const float*)d_in[8];
  const float* wo = (const float*)d_in[9];
  const float* bo = (const float*)d_in[10];
  bf16_t* ws  = (bf16_t*)d_ws;
  float*  out = (float*)d_out;

  hipLaunchKernelGGL(transpose_w, dim3(16, 16, 4), dim3(256), 0, stream, wq, wk, wv, wo, ws);
  hipLaunchKernelGGL(qkv_proj,    dim3(16, 16, 3), dim3(256), 0, stream, xq, xk, xv, bq, bk, bv, ws);
  hipLaunchKernelGGL(attn,        dim3(32, 16),    dim3(256), 0, stream, ws);
  hipLaunchKernelGGL(out_proj,    dim3(128, 16),   dim3(256), 0, stream, ws, bo, out);
}